// Round 12
// baseline (221.334 us; speedup 1.0000x reference)
//
#include <hip/hip_runtime.h>
#include <hip/hip_bf16.h>

#define B_  32
#define T_  2048
#define DH_ 1024
#define DS_ 1024
#define A_  512
#define M_  (B_ * T_)   // 65536

typedef __attribute__((ext_vector_type(8))) short bf16x8;
typedef __attribute__((ext_vector_type(4))) float f32x4;

__device__ __forceinline__ unsigned short f2bf(float f) {
    union { float f; unsigned u; } v; v.f = f;
    unsigned r = 0x7FFFu + ((v.u >> 16) & 1u);
    return (unsigned short)((v.u + r) >> 16);
}
__device__ __forceinline__ float fast_tanh(float x) {
    float cx = fminf(fmaxf(x, -9.f), 9.f);
    float e2 = __expf(2.f * cx);
    return (e2 - 1.f) / (e2 + 1.f);
}
__device__ __forceinline__ unsigned pack_bf2(float lo, float hi) {
    union { float f; unsigned u; } a, b;
    a.f = lo; b.f = hi;
    return __builtin_amdgcn_perm(b.u + 0x8000u, a.u + 0x8000u, 0x07060302u);
}

// ---- zero e [M_] ---------------------------------------------------------
__global__ void zero_e(float* __restrict__ e) {
    e[blockIdx.x * 256 + threadIdx.x] = 0.f;
}

// ---- U_t[a][k] = bf16(U_a[k][a]) -----------------------------------------
__global__ void prep_ut(const float* __restrict__ U, unsigned short* __restrict__ Ut) {
    int o = blockIdx.x * 256 + threadIdx.x;
    int a = o >> 10, k = o & (DH_ - 1);
    Ut[o] = f2bf(U[k * A_ + a]);
}

// ---- Ws[b][a] = s[b,:] . W_a[:,a]  (k-split 4-way + LDS reduce) ----------
__global__ void ws_gemv2(const float* __restrict__ s, const float* __restrict__ W,
                         float* __restrict__ Ws) {
    __shared__ float red[4][64];
    const int blk = blockIdx.x;
    const int b = blk >> 3, a0 = (blk & 7) * 64;
    const int tid = threadIdx.x;
    const int a = a0 + (tid & 63), kq = tid >> 6;
    const float* sp = s + b * DS_ + kq * 256;
    const float* wp = W + (size_t)(kq * 256) * A_ + a;
    float acc = 0.f;
#pragma unroll 8
    for (int k = 0; k < 256; ++k) acc += sp[k] * wp[(size_t)k * A_];
    red[kq][tid & 63] = acc;
    __syncthreads();
    if (tid < 64)
        Ws[b * A_ + a0 + tid] = red[0][tid] + red[1][tid] + red[2][tid] + red[3][tid];
}

// ---- main GEMM: BM=256, BN=128, BK=32, 4 waves (2Mx2N, wave 128x64).
// 2-DEEP A prefetch: loadA(t+2) issued at step t (areg double-buffer,
// static even/odd bodies), packed at t+1, consumed at t+2 -> HBM latency
// off the critical path. Uniform wrapped issue; exact counted waits:
// vmcnt(12) before pack, vmcnt(10)+lgkmcnt(0) before the single s_barrier.
// B: 3-buf gls w=16 pre-swizzled. 56 KB LDS -> 2 blocks/CU.
__global__ void __launch_bounds__(256, 2)
gemm_v5(const float* __restrict__ h,
        const unsigned short* __restrict__ Ut,
        const float* __restrict__ Ws, const float* __restrict__ va,
        float* __restrict__ e) {
    __shared__ unsigned short As[2][256][32];   // 32 KB
    __shared__ unsigned short Bs[3][128][32];   // 24 KB

    const int tid = threadIdx.x;
    const int bid0 = blockIdx.x;
    const int bid = (bid0 & 7) * 128 + (bid0 >> 3);   // XCD-chunk (nwg=1024)
    const int tn = bid & 3, tm = bid >> 2;
    const int rowBase = tm * 256, nBase = tn * 128;

    const int lane = tid & 63;
    const int wid = tid >> 6;
    const int wm = wid >> 1, wn = wid & 1;      // wave tile 128(m) x 64(n)
    const int lr = lane & 15, kg = lane >> 4;
    const int gsw = (kg ^ ((lr >> 1) & 3)) * 8;

    const int arj = tid >> 3;                   // A-staging row in 32-group
    const int acf = (tid & 7) * 4;              // f32 col
    const int ag4 = (tid & 7) >> 1;
    const int ahalf = (tid & 1) * 8;

    f32x4 acc[8][4];
#pragma unroll
    for (int i = 0; i < 8; ++i)
#pragma unroll
        for (int j = 0; j < 4; ++j) acc[i][j] = (f32x4){0.f, 0.f, 0.f, 0.f};

    auto stageB = [&](int buf, int tile) {      // 2 gls
        const int k0 = tile * 32;
#pragma unroll
        for (int j = 0; j < 2; ++j) {
            int byt = j * 4096 + tid * 16;
            int r = byt >> 6;
            int g = ((byt >> 4) & 3) ^ ((byt >> 7) & 3);
            const unsigned short* gb = Ut + (size_t)(nBase + r) * DH_ + k0 + g * 8;
            __builtin_amdgcn_global_load_lds(
                (const __attribute__((address_space(1))) unsigned int*)gb,
                (__attribute__((address_space(3))) unsigned int*)(&Bs[buf][0][0] + (byt >> 1)),
                16, 0, 0);
        }
    };
    auto loadA = [&](float4* areg, int tile) {  // 8 gloads (the vmcnt-8 unit)
        const int k0 = tile * 32;
#pragma unroll
        for (int j = 0; j < 8; ++j) {
            int row = j * 32 + arj;
            areg[j] = *(const float4*)(h + (size_t)(rowBase + row) * DH_ + k0 + acf);
        }
    };
    auto packwriteA = [&](const float4* areg, int buf) {
#pragma unroll
        for (int j = 0; j < 8; ++j) {
            int row = j * 32 + arj;
            uint2 u;
            u.x = pack_bf2(areg[j].x, areg[j].y);
            u.y = pack_bf2(areg[j].z, areg[j].w);
            int gs = ag4 ^ ((row >> 1) & 3);
            *(uint2*)((char*)&As[buf][0][0] + row * 64 + gs * 16 + ahalf) = u;
        }
    };

    float4 areg0[8], areg1[8];
    const int NT = DH_ / 32;                    // 32

    // ---- prologue (issue order fixes vmcnt semantics) ----
    loadA(areg0, 0);                            // 8
    loadA(areg1, 1);                            // 8  (16)
    __builtin_amdgcn_sched_barrier(0);
    stageB(0, 0);                               // 2  (18)
    stageB(1, 1);                               // 2  (20)
    __builtin_amdgcn_sched_barrier(0);
    asm volatile("s_waitcnt vmcnt(12)" ::: "memory");   // loadA(0) done
    __builtin_amdgcn_sched_barrier(0);
    packwriteA(areg0, 0);
    asm volatile("s_waitcnt vmcnt(10) lgkmcnt(0)" ::: "memory"); // B(0) landed
    __builtin_amdgcn_s_barrier();
    __builtin_amdgcn_sched_barrier(0);

    // ---- steady loop; even/odd bodies keep areg indexing static ----
#define STEP(T, AREG_L, AREG_W)                                               \
    {                                                                         \
        const int t_ = (T);                                                   \
        loadA(AREG_L, (t_ + 2) & 31);                                         \
        __builtin_amdgcn_sched_barrier(0);                                    \
        stageB((t_ + 2) % 3, (t_ + 2) & 31);                                  \
        __builtin_amdgcn_sched_barrier(0);                                    \
        const unsigned short* Ab = &As[t_ & 1][0][0];                         \
        const unsigned short* Bb = &Bs[t_ % 3][0][0];                         \
        bf16x8 af[8], bq[4];                                                  \
        _Pragma("unroll")                                                     \
        for (int nf = 0; nf < 4; ++nf)                                        \
            bq[nf] = *(const bf16x8*)(Bb + (wn * 64 + nf * 16 + lr) * 32 + gsw); \
        _Pragma("unroll")                                                     \
        for (int mi = 0; mi < 8; ++mi)                                        \
            af[mi] = *(const bf16x8*)(Ab + (wm * 128 + mi * 16 + lr) * 32 + gsw); \
        asm volatile("s_waitcnt lgkmcnt(0)" ::: "memory");                    \
        __builtin_amdgcn_sched_barrier(0);                                    \
        __builtin_amdgcn_s_setprio(1);                                        \
        _Pragma("unroll")                                                     \
        for (int mi = 0; mi < 8; ++mi)                                        \
            _Pragma("unroll")                                                 \
            for (int nf = 0; nf < 4; ++nf)                                    \
                acc[mi][nf] = __builtin_amdgcn_mfma_f32_16x16x32_bf16(        \
                    af[mi], bq[nf], acc[mi][nf], 0, 0, 0);                    \
        __builtin_amdgcn_s_setprio(0);                                        \
        __builtin_amdgcn_sched_barrier(0);                                    \
        asm volatile("s_waitcnt vmcnt(12)" ::: "memory");                     \
        __builtin_amdgcn_sched_barrier(0);                                    \
        if (t_ + 1 < NT) packwriteA(AREG_W, (t_ + 1) & 1);                    \
        asm volatile("s_waitcnt vmcnt(10) lgkmcnt(0)" ::: "memory");          \
        __builtin_amdgcn_s_barrier();                                         \
        __builtin_amdgcn_sched_barrier(0);                                    \
    }

#pragma unroll 1
    for (int t = 0; t < NT; t += 2) {
        STEP(t, areg0, areg1);          // consume As[t&1]; pack areg1 -> As[(t+1)&1]
        STEP(t + 1, areg1, areg0);      // consume; pack areg0
    }
#undef STEP
    asm volatile("s_waitcnt vmcnt(0) lgkmcnt(0)" ::: "memory");

    // epilogue: e[row] += sum_a tanh(acc + Ws[b][a]) * v[a]
    const int bIdx = rowBase >> 11;
    const float* WsRow = Ws + bIdx * A_;
    float wsv[4], vav[4];
#pragma unroll
    for (int nf = 0; nf < 4; ++nf) {
        int a = nBase + wn * 64 + nf * 16 + lr;
        wsv[nf] = WsRow[a];
        vav[nf] = va[a];
    }
#pragma unroll
    for (int mi = 0; mi < 8; ++mi) {
#pragma unroll
        for (int j = 0; j < 4; ++j) {
            float ssum = 0.f;
#pragma unroll
            for (int nf = 0; nf < 4; ++nf) {
                float x = acc[mi][nf][j] + wsv[nf];
                ssum += fast_tanh(x) * vav[nf];
            }
            ssum += __shfl_xor(ssum, 1);
            ssum += __shfl_xor(ssum, 2);
            ssum += __shfl_xor(ssum, 4);
            ssum += __shfl_xor(ssum, 8);
            if (lr == 0) {
                int row = rowBase + wm * 128 + mi * 16 + kg * 4 + j;
                atomicAdd(&e[row], ssum);
            }
        }
    }
}

// ---- fused softmax + context (f32 h, L3-warm): block = (b, dseg) ---------
__global__ void smax_ctx(const float* __restrict__ e, const float* __restrict__ h,
                         float* __restrict__ c) {
    __shared__ float al[T_];
    __shared__ float red[8];
    __shared__ float part[256];
    const int b = blockIdx.x >> 3, dseg = blockIdx.x & 7;
    const int tid = threadIdx.x;
    const float* ep = e + (size_t)b * T_;

    float4 v0 = ((const float4*)ep)[tid * 2];
    float4 v1 = ((const float4*)ep)[tid * 2 + 1];
    float m = fmaxf(fmaxf(fmaxf(v0.x, v0.y), fmaxf(v0.z, v0.w)),
                    fmaxf(fmaxf(v1.x, v1.y), fmaxf(v1.z, v1.w)));
#pragma unroll
    for (int off = 1; off < 64; off <<= 1) m = fmaxf(m, __shfl_xor(m, off));
    const int wv = tid >> 6;
    if ((tid & 63) == 0) red[wv] = m;
    __syncthreads();
    m = fmaxf(fmaxf(red[0], red[1]), fmaxf(red[2], red[3]));
    float e0 = __expf(v0.x - m), e1 = __expf(v0.y - m);
    float e2 = __expf(v0.z - m), e3 = __expf(v0.w - m);
    float e4 = __expf(v1.x - m), e5 = __expf(v1.y - m);
    float e6 = __expf(v1.z - m), e7 = __expf(v1.w - m);
    float ssum = e0 + e1 + e2 + e3 + e4 + e5 + e6 + e7;
#pragma unroll
    for (int off = 1; off < 64; off <<= 1) ssum += __shfl_xor(ssum, off);
    if ((tid & 63) == 0) red[4 + wv] = ssum;
    al[tid * 8 + 0] = e0; al[tid * 8 + 1] = e1;
    al[tid * 8 + 2] = e2; al[tid * 8 + 3] = e3;
    al[tid * 8 + 4] = e4; al[tid * 8 + 5] = e5;
    al[tid * 8 + 6] = e6; al[tid * 8 + 7] = e7;
    __syncthreads();
    const float inv = 1.f / (red[4] + red[5] + red[6] + red[7]);

    const int d = dseg * 128 + (tid & 127);
    const int th = tid >> 7;
    const float* hp = h + ((size_t)b * T_ + th) * DH_ + d;
    float acc = 0.f;
#pragma unroll 8
    for (int t = 0; t < T_ / 2; ++t)
        acc += al[2 * t + th] * hp[(size_t)(2 * t) * DH_];
    part[tid] = acc;
    __syncthreads();
    if (tid < 128)
        c[(size_t)b * DH_ + dseg * 128 + tid] = (part[tid] + part[tid + 128]) * inv;
}

extern "C" void kernel_launch(void* const* d_in, const int* in_sizes, int n_in,
                              void* d_out, int out_size, void* d_ws, size_t ws_size,
                              hipStream_t stream) {
    const float* s   = (const float*)d_in[0];
    const float* h   = (const float*)d_in[1];
    const float* W_a = (const float*)d_in[2];
    const float* U_a = (const float*)d_in[3];
    const float* v_a = (const float*)d_in[4];
    float* c = (float*)d_out;

    // workspace: e [65536 f32] | Ws [16384 f32] | Ut [524288 bf16]  (~1.3 MB)
    float* e  = (float*)d_ws;
    float* Ws = e + M_;
    unsigned short* Ut = (unsigned short*)(Ws + B_ * A_);

    zero_e<<<M_ / 256, 256, 0, stream>>>(e);
    prep_ut<<<(A_ * DH_) / 256, 256, 0, stream>>>(U_a, Ut);
    ws_gemv2<<<B_ * 8, 256, 0, stream>>>(s, W_a, Ws);
    gemm_v5<<<(M_ / 256) * (A_ / 128), 256, 0, stream>>>(h, Ut, Ws, v_a, e);
    smax_ctx<<<B_ * 8, 256, 0, stream>>>(e, h, c);
}